// Round 10
// baseline (752.991 us; speedup 1.0000x reference)
//
#include <hip/hip_runtime.h>

typedef unsigned int uint;
typedef unsigned short ushort;
typedef unsigned long long u64;
typedef __attribute__((ext_vector_type(8))) short short8;
typedef __attribute__((ext_vector_type(4))) float f32x4;

#define D 128

__device__ __forceinline__ float bf2f(ushort h){ return __uint_as_float(((uint)h)<<16); }
__device__ __forceinline__ ushort f2bf(float f){
  uint u = __float_as_uint(f);
  u += 0x7fff + ((u >> 16) & 1);   // RNE
  return (ushort)(u >> 16);
}
__device__ __forceinline__ float ldf(const void* p, long i, int bf){
  return bf ? bf2f(((const ushort*)p)[i]) : ((const float*)p)[i];
}
__device__ __forceinline__ int imin(int a, int b){ return a < b ? a : b; }

// ---------------- dtype detection ----------------
__global__ __launch_bounds__(256) void detect_kernel(const uint* __restrict__ xw,
                                                     int* __restrict__ flag){
  __shared__ int cnt;
  if (threadIdx.x == 0) cnt = 0;
  __syncthreads();
  uint w = xw[threadIdx.x];
  int ef = (int)((w >> 7) & 0xffu);
  if (ef >= 90 && ef <= 142) atomicAdd(&cnt, 1);
  __syncthreads();
  if (threadIdx.x == 0) flag[0] = (cnt >= 128) ? 1 : 0;
}

// ---------------- CSR build (dst/src are layer-invariant) ----------------
__global__ __launch_bounds__(256) void hist_kernel(const int* __restrict__ dst,
                                                   int* __restrict__ deg, int E_){
  int e = blockIdx.x*256 + threadIdx.x;
  if (e < E_) atomicAdd(&deg[dst[e]], 1);
}

__global__ __launch_bounds__(256) void scan1_kernel(const int* __restrict__ deg,
                                                    int* __restrict__ rs,
                                                    int* __restrict__ bsum, int Nn){
  __shared__ int s[256];
  int tid = threadIdx.x;
  int base = blockIdx.x*512;
  int i0 = base + 2*tid, i1 = i0 + 1;
  int a = (i0 < Nn) ? deg[i0] : 0;
  int b = (i1 < Nn) ? deg[i1] : 0;
  int p = a + b;
  s[tid] = p; __syncthreads();
  for (int off = 1; off < 256; off <<= 1){
    int t = (tid >= off) ? s[tid-off] : 0;
    __syncthreads();
    s[tid] += t;
    __syncthreads();
  }
  int ex = s[tid] - p;
  if (i0 < Nn) rs[i0] = ex;
  if (i1 < Nn) rs[i1] = ex + a;
  if (tid == 255) bsum[blockIdx.x] = s[255];
}

__global__ __launch_bounds__(256) void scan2_kernel(const int* __restrict__ bsum,
                                                    int* __restrict__ boff, int NB){
  __shared__ int s[256];
  int tid = threadIdx.x;
  int v = (tid < NB) ? bsum[tid] : 0;
  s[tid] = v; __syncthreads();
  for (int off = 1; off < 256; off <<= 1){
    int t = (tid >= off) ? s[tid-off] : 0;
    __syncthreads();
    s[tid] += t;
    __syncthreads();
  }
  boff[tid] = s[tid] - v;
}

__global__ __launch_bounds__(256) void scan3_kernel(int* __restrict__ rs,
                                                    const int* __restrict__ boff,
                                                    int* __restrict__ cursor,
                                                    int Nn, int E_){
  int i = blockIdx.x*256 + threadIdx.x;
  if (i < Nn){
    int v = rs[i] + boff[i >> 9];
    rs[i] = v;
    cursor[i] = v;
  }
  if (i == 0) rs[Nn] = E_;
}

// fused scatter + CSR-order pack: streaming attr read, scattered writes
__global__ __launch_bounds__(256) void scatterpack_kernel(
    const int* __restrict__ dst, const int* __restrict__ src,
    const void* __restrict__ eattr, int* __restrict__ cursor,
    int* __restrict__ sarr, ushort* __restrict__ paHi, ushort* __restrict__ paLo,
    int E_, const int* __restrict__ flag)
{
  int e = blockIdx.x*256 + threadIdx.x;
  if (e >= E_) return;
  int bf = flag[0];
  int pos = atomicAdd(&cursor[dst[e]], 1);
  sarr[pos] = src[e];
  ushort hv[16], lv[16];
  #pragma unroll
  for (int k = 0; k < 16; k++){
    float v = ldf(eattr, (long)e*16 + k, bf);
    ushort h = f2bf(v);
    hv[k] = h;
    lv[k] = f2bf(v - bf2f(h));
  }
  *(uint4*)(paHi + (long)pos*16)     = *(uint4*)&hv[0];
  *(uint4*)(paHi + (long)pos*16 + 8) = *(uint4*)&hv[8];
  *(uint4*)(paLo + (long)pos*16)     = *(uint4*)&lv[0];
  *(uint4*)(paLo + (long)pos*16 + 8) = *(uint4*)&lv[8];
}

// ---------------- MLP W transpose + hi/lo split (w1 and w2 in one launch) ----------------
__global__ __launch_bounds__(256) void trans_mlp_kernel(
    const void* __restrict__ w1p, const void* __restrict__ w2p,
    ushort* __restrict__ h1, ushort* __restrict__ l1,
    ushort* __restrict__ h2, ushort* __restrict__ l2,
    const int* __restrict__ flag)
{
  int bf = flag[0];
  int idx = blockIdx.x*256 + threadIdx.x;    // grid covers 2*49152 exactly
  const void* W; ushort *hi, *lo; int id;
  if (idx < 49152){ W = w1p; hi = h1; lo = l1; id = idx; }
  else            { W = w2p; hi = h2; lo = l2; id = idx - 49152; }
  int l = id >> 14, rem = id & 16383, k = rem >> 7, n = rem & 127;
  float w = ldf(W, id, bf);
  ushort h = f2bf(w);
  int di = (l << 14) | (n << 7) | k;
  hi[di] = h;
  lo[di] = f2bf(w - bf2f(h));
}

// edge-W transpose: ew[l][k(16)][n(128)] -> [l][n][k(16)] hi/lo bf16
__global__ __launch_bounds__(256) void trans_edge_kernel(const void* __restrict__ W,
                                                         ushort* __restrict__ hi,
                                                         ushort* __restrict__ lo,
                                                         const int* __restrict__ flag){
  int bf = flag[0];
  int idx = blockIdx.x*256 + threadIdx.x;   // grid covers 3*2048 exactly
  int l = idx >> 11, rem = idx & 2047, k = rem >> 7, n = rem & 127;
  float w = ldf(W, idx, bf);
  ushort h = f2bf(w);
  int di = (l << 11) | (n << 4) | k;
  hi[di] = h;
  lo[di] = f2bf(w - bf2f(h));
}

// ---------------- fused layer: edge gather-agg + PRE + MLP + pool ----------------
// hpre stays in registers/LDS; out = relu(hpre@W1+b1)@W2+b2; pool into gbuf.
template<bool FIRST>
__global__ __launch_bounds__(256) void fused_layer(
    const int* __restrict__ sarr, const int* __restrict__ rs,
    const ushort* __restrict__ paHi, const ushort* __restrict__ paLo,
    const ushort* __restrict__ weHi, const ushort* __restrict__ weLo,
    const void* __restrict__ eb, const void* __restrict__ vn,
    const void* __restrict__ epsp, int layer,
    const void* __restrict__ xin, const float* __restrict__ xws,
    const ushort* __restrict__ w1hi, const ushort* __restrict__ w1lo,
    const ushort* __restrict__ w2hi, const ushort* __restrict__ w2lo,
    const void* __restrict__ b1v, const void* __restrict__ b2v,
    float* __restrict__ outp, int Nn, const int* __restrict__ flag,
    const int* __restrict__ batch, float* __restrict__ gbuf, int colOff)
{
  int bf = flag[0];
  // eemb (edge phase) and sbuf (mlp staging) alias the same region
  __shared__ __attribute__((aligned(16))) char uni[34816];
  float  (*eemb)[16][132] = (float  (*)[16][132])uni;   // [4][16][132] = 33792 B
  ushort (*sbuf)[64][136] = (ushort (*)[64][136])uni;   // [2][64][136] = 34816 B
  __shared__ float bias1[D], bias2[D];
  __shared__ int bseg[64];
  __shared__ float gpart[8][132];

  int tid = threadIdx.x;
  int lane = tid & 63, wvi = tid >> 6;
  int m_ = lane & 15, q = lane >> 4;
  int hh = lane >> 5, c4 = (lane & 31) << 2;

  // loop-invariant edge-W B-frags
  short8 bW1[8], bW2[8];
  #pragma unroll
  for (int ci = 0; ci < 8; ci++){
    int cc = ci*16 + m_;
    bW1[ci] = *(const short8*)(weHi + cc*16 + (q&1)*8);
    bW2[ci] = *(const short8*)(weLo + cc*16 + (q&1)*8);
  }
  const ushort* pa = (q < 2) ? paHi : paLo;

  f32x4 vn4, cv4;
  #pragma unroll
  for (int j = 0; j < 4; j++){
    vn4[j] = ldf(vn, (long)layer*128 + c4 + j, bf);
    cv4[j] = ldf(eb, (long)layer*128 + c4 + j, bf) + vn4[j];
  }
  float epsv = 1.f + ldf(epsp, layer, bf);
  const float* xp32 = FIRST ? (const float*)xin : xws;

  long base = (long)blockIdx.x*64 + wvi*16;
  f32x4 hpacc[8];

  // -------- edge phase: wave handles 8 node-pairs --------
  #pragma unroll
  for (int p = 0; p < 8; p++){
    long n0 = base + 2*p;
    f32x4 hp = {0.f,0.f,0.f,0.f};
    if (n0 < Nn){
      int beg   = rs[n0];
      int split = rs[n0+1];
      int end   = (n0+2 <= Nn) ? rs[n0+2] : split;
      f32x4 accA = {0.f,0.f,0.f,0.f}, accB = {0.f,0.f,0.f,0.f};
      int scur = (beg < end) ? sarr[imin(beg + m_, end - 1)] : 0;
      for (int ii = beg; ii < end; ii += 16){
        short8 afrag = *(const short8*)(pa + (long)imin(ii + m_, end - 1)*16 + (q&1)*8);
        bool more = (ii + 16) < end;
        int snext = more ? sarr[imin(ii + 16 + m_, end - 1)] : scur;
        // e_emb via MFMA -> wave LDS (skip W_lo when storage is bf16)
        #pragma unroll
        for (int ci = 0; ci < 8; ci++){
          f32x4 acc = {0.f,0.f,0.f,0.f};
          acc = __builtin_amdgcn_mfma_f32_16x16x32_bf16(afrag, bW1[ci], acc, 0, 0, 0);
          if (!bf) acc = __builtin_amdgcn_mfma_f32_16x16x32_bf16(afrag, bW2[ci], acc, 0, 0, 0);
          int cc = ci*16 + m_;
          #pragma unroll
          for (int rg = 0; rg < 4; rg++) eemb[wvi][q*4+rg][cc] = acc[rg];
        }
        // x-gathers: lane half hh covers edge 2jj+hh, 4 dims (16B) each
        int ssl[8];
        #pragma unroll
        for (int jj = 0; jj < 8; jj++) ssl[jj] = __shfl(scur, 2*jj + hh);
        f32x4 xv[8];
        #pragma unroll
        for (int jj = 0; jj < 8; jj++){
          if (FIRST && bf){
            uint2 u = *(const uint2*)((const ushort*)xin + (long)ssl[jj]*D + c4);
            xv[jj][0] = __uint_as_float(u.x << 16);
            xv[jj][1] = __uint_as_float(u.x & 0xffff0000u);
            xv[jj][2] = __uint_as_float(u.y << 16);
            xv[jj][3] = __uint_as_float(u.y & 0xffff0000u);
          } else {
            xv[jj] = *(const f32x4*)(xp32 + (long)ssl[jj]*D + c4);
          }
        }
        #pragma unroll
        for (int jj = 0; jj < 8; jj++){
          int gidx = ii + 2*jj + hh;
          f32x4 ee = *(const f32x4*)&eemb[wvi][2*jj + hh][c4];
          bool inA = gidx < split;
          bool inB = (!inA) && (gidx < end);
          #pragma unroll
          for (int j = 0; j < 4; j++){
            float r = fmaxf(cv4[j] + xv[jj][j] + ee[j], 0.f);
            accA[j] += inA ? r : 0.f;
            accB[j] += inB ? r : 0.f;
          }
        }
        scur = snext;
      }
      // cross-half reduce; half hh owns row n0+hh
      long row = n0 + hh;
      f32x4 sel;
      #pragma unroll
      for (int j = 0; j < 4; j++){
        float a = accA[j] + __shfl_xor(accA[j], 32);
        float b = accB[j] + __shfl_xor(accB[j], 32);
        sel[j] = hh ? b : a;
      }
      if (row < Nn){
        f32x4 xn;
        if (FIRST && bf){
          uint2 u = *(const uint2*)((const ushort*)xin + row*D + c4);
          xn[0] = __uint_as_float(u.x << 16);
          xn[1] = __uint_as_float(u.x & 0xffff0000u);
          xn[2] = __uint_as_float(u.y << 16);
          xn[3] = __uint_as_float(u.y & 0xffff0000u);
        } else {
          xn = *(const f32x4*)(xp32 + row*D + c4);
        }
        #pragma unroll
        for (int j = 0; j < 4; j++) hp[j] = epsv*(xn[j] + vn4[j]) + sel[j];
      }
    }
    hpacc[p] = hp;
  }
  __syncthreads();          // edge phase done in ALL waves; eemb dead

  // -------- stage hpre -> sbuf (hi/lo bf16), init mlp shared state --------
  #pragma unroll
  for (int p = 0; p < 8; p++){
    int rl = wvi*16 + 2*p + hh;
    u64 hv = 0, lv = 0;
    #pragma unroll
    for (int j = 0; j < 4; j++){
      ushort h_ = f2bf(hpacc[p][j]);
      ushort l_ = f2bf(hpacc[p][j] - bf2f(h_));
      hv |= ((u64)h_) << (16*j);
      lv |= ((u64)l_) << (16*j);
    }
    *(u64*)&sbuf[0][rl][c4] = hv;
    *(u64*)&sbuf[1][rl][c4] = lv;
  }
  if (tid < D){
    bias1[tid] = ldf(b1v, (long)layer*D + tid, bf);
    bias2[tid] = ldf(b2v, (long)layer*D + tid, bf);
  }
  if (tid < 64){
    long rr = (long)blockIdx.x*64 + tid;
    bseg[tid] = batch[(rr < Nn) ? rr : (Nn - 1)];
  }
  for (int i = tid; i < 8*132; i += 256) ((float*)gpart)[i] = 0.f;
  __syncthreads();

  // -------- MLP phase --------
  int bmin = bseg[0], bmax = bseg[63];
  int nseg = bmax - bmin + 1;
  bool useL = (nseg <= 8);

  int m = lane & 15, kq = lane >> 4;
  int lr = wvi*16 + m;
  short8 aHi[4], aLo[4];
  #pragma unroll
  for (int ki = 0; ki < 4; ki++){
    aHi[ki] = *(const short8*)&sbuf[0][lr][ki*32 + kq*8];
    aLo[ki] = *(const short8*)&sbuf[1][lr][ki*32 + kq*8];
  }
  float h1[8][4];
  #pragma unroll
  for (int ci = 0; ci < 8; ci++){
    int c = ci*16 + m;
    f32x4 acc;
    float bv = bias1[c];
    acc[0] = bv; acc[1] = bv; acc[2] = bv; acc[3] = bv;
    const ushort* bp = w1hi + ((long)c << 7) + kq*8;
    #pragma unroll
    for (int ki = 0; ki < 4; ki++){
      short8 bfr = *(const short8*)(bp + ki*32);
      acc = __builtin_amdgcn_mfma_f32_16x16x32_bf16(aHi[ki], bfr, acc, 0, 0, 0);
      acc = __builtin_amdgcn_mfma_f32_16x16x32_bf16(aLo[ki], bfr, acc, 0, 0, 0);
    }
    if (!bf){
      const ushort* blp = w1lo + ((long)c << 7) + kq*8;
      #pragma unroll
      for (int ki = 0; ki < 4; ki++){
        short8 blr = *(const short8*)(blp + ki*32);
        acc = __builtin_amdgcn_mfma_f32_16x16x32_bf16(aHi[ki], blr, acc, 0, 0, 0);
      }
    }
    #pragma unroll
    for (int rg = 0; rg < 4; rg++) h1[ci][rg] = fmaxf(acc[rg], 0.f);
  }
  __syncthreads();
  uint* h1p = (uint*)&sbuf[0][0][0];   // 64*132 uints fit in uni
  #pragma unroll
  for (int ci = 0; ci < 8; ci++){
    int c = ci*16 + m;
    #pragma unroll
    for (int rg = 0; rg < 4; rg++){
      int rl = wvi*16 + kq*4 + rg;
      float v = h1[ci][rg];
      ushort hi_ = f2bf(v);
      ushort lo_ = f2bf(v - bf2f(hi_));
      h1p[rl*132 + c] = ((uint)hi_ << 16) | (uint)lo_;
    }
  }
  __syncthreads();
  #pragma unroll
  for (int ki = 0; ki < 4; ki++){
    const uint* up = h1p + lr*132 + ki*32 + kq*8;
    uint4 ua = *(const uint4*)up;
    uint4 ub = *(const uint4*)(up + 4);
    uint uu[8] = {ua.x,ua.y,ua.z,ua.w, ub.x,ub.y,ub.z,ub.w};
    short8 ah, al;
    #pragma unroll
    for (int t = 0; t < 8; t++){
      ah[t] = (short)(uu[t] >> 16);
      al[t] = (short)(uu[t] & 0xffffu);
    }
    aHi[ki] = ah; aLo[ki] = al;
  }
  int rl0 = wvi*16 + kq*4;
  long rowBase = (long)blockIdx.x*64 + rl0;
  int s0 = bseg[rl0], s3 = bseg[rl0+3];
  #pragma unroll
  for (int ci = 0; ci < 8; ci++){
    int c = ci*16 + m;
    f32x4 acc;
    float bv = bias2[c];
    acc[0] = bv; acc[1] = bv; acc[2] = bv; acc[3] = bv;
    const ushort* bp = w2hi + ((long)c << 7) + kq*8;
    #pragma unroll
    for (int ki = 0; ki < 4; ki++){
      short8 bfr = *(const short8*)(bp + ki*32);
      acc = __builtin_amdgcn_mfma_f32_16x16x32_bf16(aHi[ki], bfr, acc, 0, 0, 0);
      acc = __builtin_amdgcn_mfma_f32_16x16x32_bf16(aLo[ki], bfr, acc, 0, 0, 0);
    }
    if (!bf){
      const ushort* blp = w2lo + ((long)c << 7) + kq*8;
      #pragma unroll
      for (int ki = 0; ki < 4; ki++){
        short8 blr = *(const short8*)(blp + ki*32);
        acc = __builtin_amdgcn_mfma_f32_16x16x32_bf16(aHi[ki], blr, acc, 0, 0, 0);
      }
    }
    #pragma unroll
    for (int rg = 0; rg < 4; rg++){
      long orow = rowBase + rg;
      if (orow < Nn) outp[orow*D + c] = acc[rg];
    }
    if (useL){
      if (s0 == s3 && rowBase + 3 < Nn){
        atomicAdd(&gpart[s0 - bmin][c], acc[0] + acc[1] + acc[2] + acc[3]);
      } else {
        #pragma unroll
        for (int rg = 0; rg < 4; rg++){
          if (rowBase + rg < Nn)
            atomicAdd(&gpart[bseg[rl0+rg] - bmin][c], acc[rg]);
        }
      }
    } else {
      #pragma unroll
      for (int rg = 0; rg < 4; rg++){
        if (rowBase + rg < Nn)
          unsafeAtomicAdd(&gbuf[(long)bseg[rl0+rg]*384 + colOff + c], acc[rg]);
      }
    }
  }
  if (useL){
    __syncthreads();
    if (tid < 128){
      for (int s = 0; s < nseg; s++){
        float v = gpart[s][tid];
        if (v != 0.f)
          unsafeAtomicAdd(&gbuf[(long)(bmin + s)*384 + colOff + tid], v);
      }
    }
  }
}

// ---------------- head: Linear->LN->ReLU x2 -> Linear ----------------
__global__ __launch_bounds__(256) void head_kernel(
    const float* __restrict__ g,
    const void* __restrict__ w1, const void* __restrict__ b1,
    const void* __restrict__ g1, const void* __restrict__ be1,
    const void* __restrict__ w2, const void* __restrict__ b2,
    const void* __restrict__ g2, const void* __restrict__ be2,
    const void* __restrict__ ow, const void* __restrict__ ob,
    void* __restrict__ outp, const int* __restrict__ flag)
{
  int bf = flag[0];
  __shared__ float grow[384];
  __shared__ float h1[256];
  __shared__ float h2[128];
  __shared__ float redA[4], redB[4], stats[2];
  int b = blockIdx.x, tid = threadIdx.x;
  for (int i = tid; i < 384; i += 256) grow[i] = g[(long)b*384 + i];
  __syncthreads();
  float v = ldf(b1, tid, bf);
  for (int k = 0; k < 384; k++) v += grow[k] * ldf(w1, (long)k*256 + tid, bf);
  float s = v, s2 = v*v;
  for (int o = 32; o; o >>= 1){ s += __shfl_down(s,o); s2 += __shfl_down(s2,o); }
  if ((tid & 63) == 0){ redA[tid>>6] = s; redB[tid>>6] = s2; }
  __syncthreads();
  if (tid == 0){
    float S = redA[0]+redA[1]+redA[2]+redA[3];
    float S2 = redB[0]+redB[1]+redB[2]+redB[3];
    float mu = S / 256.f;
    stats[0] = mu; stats[1] = rsqrtf(S2/256.f - mu*mu + 1e-5f);
  }
  __syncthreads();
  float y = (v - stats[0]) * stats[1] * ldf(g1, tid, bf) + ldf(be1, tid, bf);
  h1[tid] = fmaxf(y, 0.f);
  __syncthreads();
  float v2 = 0.f;
  if (tid < 128){
    v2 = ldf(b2, tid, bf);
    for (int k = 0; k < 256; k++) v2 += h1[k] * ldf(w2, (long)k*128 + tid, bf);
  }
  float t = (tid < 128) ? v2 : 0.f;
  s = t; s2 = t*t;
  for (int o = 32; o; o >>= 1){ s += __shfl_down(s,o); s2 += __shfl_down(s2,o); }
  if ((tid & 63) == 0){ redA[tid>>6] = s; redB[tid>>6] = s2; }
  __syncthreads();
  if (tid == 0){
    float S = redA[0]+redA[1]+redA[2]+redA[3];
    float S2 = redB[0]+redB[1]+redB[2]+redB[3];
    float mu = S / 128.f;
    stats[0] = mu; stats[1] = rsqrtf(S2/128.f - mu*mu + 1e-5f);
  }
  __syncthreads();
  if (tid < 128){
    float y2 = (v2 - stats[0]) * stats[1] * ldf(g2, tid, bf) + ldf(be2, tid, bf);
    h2[tid] = fmaxf(y2, 0.f);
  }
  __syncthreads();
  float p = (tid < 128) ? h2[tid] * ldf(ow, tid, bf) : 0.f;
  s = p;
  for (int o = 32; o; o >>= 1) s += __shfl_down(s, o);
  if ((tid & 63) == 0) redA[tid>>6] = s;
  __syncthreads();
  if (tid == 0){
    float r = redA[0]+redA[1]+redA[2]+redA[3] + ldf(ob, 0, bf);
    if (bf) ((ushort*)outp)[b] = f2bf(r);
    else    ((float*)outp)[b]  = r;
  }
}

extern "C" void kernel_launch(void* const* d_in, const int* in_sizes, int n_in,
                              void* d_out, int out_size, void* d_ws, size_t ws_size,
                              hipStream_t stream)
{
  const void* x_in  = d_in[0];
  const int*  eidx  = (const int*)d_in[1];
  const void* eattr = d_in[2];
  const int*  batch = (const int*)d_in[3];
  const void* vn    = d_in[4];
  const void* ew    = d_in[5];
  const void* eb    = d_in[6];
  const void* epsp  = d_in[7];
  const void* w1p   = d_in[8];
  const void* b1p   = d_in[9];
  const void* w2p   = d_in[10];
  const void* b2p   = d_in[11];
  const void* lw1   = d_in[12];
  const void* lb1   = d_in[13];
  const void* ln1g  = d_in[14];
  const void* ln1b  = d_in[15];
  const void* lw2   = d_in[16];
  const void* lb2   = d_in[17];
  const void* ln2g  = d_in[18];
  const void* ln2b  = d_in[19];
  const void* owp   = d_in[20];
  const void* obp   = d_in[21];

  int Nn = in_sizes[0] / D;     // 50000
  int Ee = in_sizes[1] / 2;     // 600000
  int Gg = out_size;            // 512
  const int* srcp = eidx;
  const int* dstp = eidx + Ee;

  float*  B     = (float*)d_ws;                 // layer out ping
  float*  C     = B + (size_t)Nn*D;             // layer out pong
  float*  gbuf  = C + (size_t)Nn*D;
  ushort* wT1hi = (ushort*)(gbuf + (size_t)Gg*384);
  ushort* wT1lo = wT1hi + 3*D*D;
  ushort* wT2hi = wT1lo + 3*D*D;
  ushort* wT2lo = wT2hi + 3*D*D;
  ushort* weHi  = wT2lo + 3*D*D;      // [3][128][16]
  ushort* weLo  = weHi + 3*128*16;
  int*    flag  = (int*)(weLo + 3*128*16);
  int*    deg     = flag + 1;
  int*    rs      = deg + Nn;        // N+1
  int*    cursor  = rs + Nn + 1;
  int*    bsum    = cursor + Nn;
  int*    boff    = bsum + 256;
  int*    sarr    = boff + 256;                   // [E]
  ushort* paHi    = (ushort*)(sarr + Ee);         // [E][16]
  ushort* paLo    = paHi + (size_t)Ee*16;         // [E][16]

  detect_kernel<<<1,256,0,stream>>>((const uint*)x_in, flag);

  // CSR build (once; dst/src invariant across layers)
  int NB = (Nn + 511) / 512;
  hipMemsetAsync(deg, 0, (size_t)Nn*sizeof(int), stream);
  hipMemsetAsync(gbuf, 0, (size_t)Gg*384*sizeof(float), stream);
  hist_kernel<<<(Ee+255)/256,256,0,stream>>>(dstp, deg, Ee);
  scan1_kernel<<<NB,256,0,stream>>>(deg, rs, bsum, Nn);
  scan2_kernel<<<1,256,0,stream>>>(bsum, boff, NB);
  scan3_kernel<<<(Nn+255)/256,256,0,stream>>>(rs, boff, cursor, Nn, Ee);
  scatterpack_kernel<<<(Ee+255)/256,256,0,stream>>>(dstp, srcp, eattr, cursor,
                                                    sarr, paHi, paLo, Ee, flag);
  trans_mlp_kernel<<<384,256,0,stream>>>(w1p, w2p, wT1hi, wT1lo, wT2hi, wT2lo, flag);
  trans_edge_kernel<<<24,256,0,stream>>>(ew, weHi, weLo, flag);

  int grid = (Nn + 63) / 64;    // 782
  float* xcur = nullptr;
  for (int i = 0; i < 3; i++){
    float* out = (i == 1) ? C : B;    // L0->B, L1->C, L2->B
    if (i == 0)
      fused_layer<true ><<<grid,256,0,stream>>>(sarr, rs, paHi, paLo,
          weHi + (size_t)i*2048, weLo + (size_t)i*2048, eb, vn, epsp, i,
          x_in, nullptr,
          wT1hi + (size_t)i*D*D, wT1lo + (size_t)i*D*D,
          wT2hi + (size_t)i*D*D, wT2lo + (size_t)i*D*D,
          b1p, b2p, out, Nn, flag, batch, gbuf, i*D);
    else
      fused_layer<false><<<grid,256,0,stream>>>(sarr, rs, paHi, paLo,
          weHi + (size_t)i*2048, weLo + (size_t)i*2048, eb, vn, epsp, i,
          nullptr, xcur,
          wT1hi + (size_t)i*D*D, wT1lo + (size_t)i*D*D,
          wT2hi + (size_t)i*D*D, wT2lo + (size_t)i*D*D,
          b1p, b2p, out, Nn, flag, batch, gbuf, i*D);
    xcur = out;
  }
  head_kernel<<<Gg,256,0,stream>>>(gbuf, lw1, lb1, ln1g, ln1b,
                                   lw2, lb2, ln2g, ln2b, owp, obp, d_out, flag);
}